// Round 1
// baseline (740.163 us; speedup 1.0000x reference)
//
#include <hip/hip_runtime.h>
#include <cstddef>

#define B_ 16
#define N_ 4096
#define C_ 1024
#define H_ 16
#define D_ 64
#define HD_ 1024

// ---------------------------------------------------------------------------
// Kernel A: per (b,h): q[b,h,:] = x[b,0,:] @ Wq_h, scaled; then
//           u[b,h,c] = sum_d q[d] * Wkv[c, h*64+d]   (k-half of Wkv)
// grid = B*H = 256 blocks, 256 threads
// ---------------------------------------------------------------------------
__global__ __launch_bounds__(256) void kA(const float* __restrict__ x,
                                          const float* __restrict__ Wq,
                                          const float* __restrict__ Wkv,
                                          float* __restrict__ u) {
  const int b = blockIdx.x >> 4;
  const int h = blockIdx.x & 15;
  __shared__ float xr[C_];
  __shared__ float qp[4][D_];
  __shared__ float qs[D_];
  const float* xb = x + (size_t)b * N_ * C_;  // row n=0
  for (int c = threadIdx.x; c < C_; c += 256) xr[c] = xb[c];
  __syncthreads();
  const int d = threadIdx.x & 63;
  const int part = threadIdx.x >> 6;
  float a = 0.f;
  const float* wq = Wq + h * D_ + d;
  #pragma unroll 4
  for (int c = part * 256; c < part * 256 + 256; ++c)
    a += xr[c] * wq[(size_t)c * HD_];
  qp[part][d] = a;
  __syncthreads();
  if (threadIdx.x < 64) {
    qs[threadIdx.x] = (qp[0][threadIdx.x] + qp[1][threadIdx.x] +
                       qp[2][threadIdx.x] + qp[3][threadIdx.x]) * 0.125f;  // D^-0.5
  }
  __syncthreads();
  for (int c = threadIdx.x; c < C_; c += 256) {
    const float4* wr = (const float4*)(Wkv + (size_t)c * (2 * HD_) + h * D_);
    float s = 0.f;
    #pragma unroll
    for (int d4 = 0; d4 < 16; ++d4) {
      float4 wv = wr[d4];
      s += wv.x * qs[4 * d4] + wv.y * qs[4 * d4 + 1] +
           wv.z * qs[4 * d4 + 2] + wv.w * qs[4 * d4 + 3];
    }
    u[(size_t)blockIdx.x * C_ + c] = s;
  }
}

// ---------------------------------------------------------------------------
// Kernel B: logits. s[b,h,n] = x[b,n,:] . u[b,h,:], 4-way split over c.
// grid = 1024 blocks: q = bid&3 (c-quarter), chunk = (bid>>2)&15, b = bid>>6
// thread -> one row n; u loads are wave-uniform -> scalar loads.
// spart layout: [q][b][h][n]
// ---------------------------------------------------------------------------
__global__ __launch_bounds__(256) void kB(const float* __restrict__ x,
                                          const float* __restrict__ u,
                                          float* __restrict__ spart) {
  const int q = blockIdx.x & 3;
  const int chunk = (blockIdx.x >> 2) & 15;
  const int b = blockIdx.x >> 6;
  const int n = chunk * 256 + threadIdx.x;
  const float4* xr = (const float4*)(x + ((size_t)b * N_ + n) * C_ + q * 256);
  const float* ub = u + (size_t)b * H_ * C_ + q * 256;
  float acc[H_];
  #pragma unroll
  for (int h = 0; h < H_; ++h) acc[h] = 0.f;
  #pragma unroll 4
  for (int c4 = 0; c4 < 64; ++c4) {
    const float4 xv = xr[c4];
    #pragma unroll
    for (int h = 0; h < H_; ++h) {
      const float4 uv = *(const float4*)(ub + (size_t)h * C_ + c4 * 4);
      acc[h] += xv.x * uv.x + xv.y * uv.y + xv.z * uv.z + xv.w * uv.w;
    }
  }
  const size_t base = ((size_t)q * B_ * H_ + (size_t)b * H_) * N_ + n;
  #pragma unroll
  for (int h = 0; h < H_; ++h) spart[base + (size_t)h * N_] = acc[h];
}

// ---------------------------------------------------------------------------
// Kernel C: softmax over n per (b,h). Sums the 4 c-quarters, max, exp, sum.
// Writes p transposed [b][n][h] (so kernel D can scalar-load 16 p's per row)
// and denominator l[b*16+h].
// ---------------------------------------------------------------------------
__global__ __launch_bounds__(256) void kC(const float* __restrict__ spart,
                                          float* __restrict__ p,
                                          float* __restrict__ l) {
  const int bh = blockIdx.x;
  const int b = bh >> 4;
  const int h = bh & 15;
  __shared__ float red[256];
  const size_t base = (size_t)bh * N_;
  const size_t slab = (size_t)B_ * H_ * N_;
  const float* s0 = spart + base;
  const float* s1 = spart + slab + base;
  const float* s2 = spart + 2 * slab + base;
  const float* s3 = spart + 3 * slab + base;
  float sv[16];
  float m = -1e30f;
  #pragma unroll
  for (int i = 0; i < 16; ++i) {
    const int n = threadIdx.x + i * 256;
    const float v = s0[n] + s1[n] + s2[n] + s3[n];
    sv[i] = v;
    m = fmaxf(m, v);
  }
  red[threadIdx.x] = m;
  __syncthreads();
  for (int off = 128; off; off >>= 1) {
    if (threadIdx.x < off)
      red[threadIdx.x] = fmaxf(red[threadIdx.x], red[threadIdx.x + off]);
    __syncthreads();
  }
  m = red[0];
  __syncthreads();
  float sum = 0.f;
  #pragma unroll
  for (int i = 0; i < 16; ++i) {
    const float e = expf(sv[i] - m);
    sv[i] = e;
    sum += e;
  }
  red[threadIdx.x] = sum;
  __syncthreads();
  for (int off = 128; off; off >>= 1) {
    if (threadIdx.x < off) red[threadIdx.x] += red[threadIdx.x + off];
    __syncthreads();
  }
  if (threadIdx.x == 0) l[bh] = red[0];
  #pragma unroll
  for (int i = 0; i < 16; ++i) {
    const int n = threadIdx.x + i * 256;
    p[((size_t)b * N_ + n) * H_ + h] = sv[i];
  }
}

// ---------------------------------------------------------------------------
// Kernel D: w_part[b,s,h,:] = sum_{n in chunk s} p[b,h,n] * x[b,n,:]
// grid = (S, B). thread t owns c-slice [4t,4t+4) for all 16 heads (64 acc regs).
// x rows are read fully coalesced (block-wide float4 = one row).
// p reads are block-uniform -> scalar loads.
// ---------------------------------------------------------------------------
__global__ __launch_bounds__(256) void kD(const float* __restrict__ x,
                                          const float* __restrict__ p,
                                          float* __restrict__ wpart, int rpc) {
  const int s = blockIdx.x;
  const int b = blockIdx.y;
  const int S = gridDim.x;
  float4 acc[H_];
  #pragma unroll
  for (int h = 0; h < H_; ++h) acc[h] = make_float4(0.f, 0.f, 0.f, 0.f);
  const int n0 = s * rpc;
  for (int r = 0; r < rpc; ++r) {
    const int n = n0 + r;
    const float4 xv =
        *(const float4*)(x + ((size_t)b * N_ + n) * C_ + threadIdx.x * 4);
    const float4* pp = (const float4*)(p + ((size_t)b * N_ + n) * H_);
    const float4 p0 = pp[0], p1 = pp[1], p2 = pp[2], p3 = pp[3];
    float pv[16];
    pv[0] = p0.x; pv[1] = p0.y; pv[2] = p0.z; pv[3] = p0.w;
    pv[4] = p1.x; pv[5] = p1.y; pv[6] = p1.z; pv[7] = p1.w;
    pv[8] = p2.x; pv[9] = p2.y; pv[10] = p2.z; pv[11] = p2.w;
    pv[12] = p3.x; pv[13] = p3.y; pv[14] = p3.z; pv[15] = p3.w;
    #pragma unroll
    for (int h = 0; h < H_; ++h) {
      acc[h].x += pv[h] * xv.x;
      acc[h].y += pv[h] * xv.y;
      acc[h].z += pv[h] * xv.z;
      acc[h].w += pv[h] * xv.w;
    }
  }
  float* wp = wpart + (((size_t)b * S + s) * H_) * C_ + threadIdx.x * 4;
  #pragma unroll
  for (int h = 0; h < H_; ++h) *(float4*)(wp + (size_t)h * C_) = acc[h];
}

// ---------------------------------------------------------------------------
// Kernel R: w[b,h,c] = (sum_s wpart[b,s,h,c]) / l[b,h]
// ---------------------------------------------------------------------------
__global__ __launch_bounds__(256) void kR(const float* __restrict__ wpart,
                                          const float* __restrict__ l,
                                          float* __restrict__ w, int S) {
  const size_t gid = (size_t)blockIdx.x * 256 + threadIdx.x;  // < 262144
  const int b = (int)(gid >> 14);
  const int rem = (int)(gid & 16383);  // h*1024 + c
  const int h = rem >> 10;
  const float* base = wpart + (size_t)b * S * (H_ * C_) + rem;
  float sum = 0.f;
  for (int s = 0; s < S; ++s) sum += base[(size_t)s * (H_ * C_)];
  w[gid] = sum / l[b * H_ + h];
}

// ---------------------------------------------------------------------------
// Kernel E1: cls[b,hd] = w[b,h,:] . Wkv[:, 1024+hd]   (v-half of Wkv)
// ---------------------------------------------------------------------------
__global__ __launch_bounds__(256) void kE1(const float* __restrict__ w,
                                           const float* __restrict__ Wkv,
                                           float* __restrict__ cls) {
  const int gid = blockIdx.x * 256 + threadIdx.x;  // < 16384
  const int b = gid >> 10;
  const int hd = gid & 1023;
  const int h = hd >> 6;
  const float* wr = w + ((size_t)b * H_ + h) * C_;  // wave-uniform -> s_load
  const float* wv = Wkv + HD_ + hd;                 // coalesced across hd
  float acc = 0.f;
  #pragma unroll 8
  for (int c = 0; c < C_; ++c) acc += wr[c] * wv[(size_t)c * (2 * HD_)];
  cls[gid] = acc;
}

// ---------------------------------------------------------------------------
// Kernel E2: out[b,j] = bproj[j] + cls[b,:] . Wproj[:,j]
// ---------------------------------------------------------------------------
__global__ __launch_bounds__(256) void kE2(const float* __restrict__ cls,
                                           const float* __restrict__ Wproj,
                                           const float* __restrict__ bproj,
                                           float* __restrict__ out) {
  const int gid = blockIdx.x * 256 + threadIdx.x;  // < 16384
  const int b = gid >> 10;
  const int j = gid & 1023;
  const float* cb = cls + (size_t)b * HD_;  // wave-uniform -> s_load
  float acc = bproj[j];
  #pragma unroll 8
  for (int i = 0; i < HD_; ++i) acc += cb[i] * Wproj[(size_t)i * C_ + j];
  out[gid] = acc;
}

extern "C" void kernel_launch(void* const* d_in, const int* in_sizes, int n_in,
                              void* d_out, int out_size, void* d_ws,
                              size_t ws_size, hipStream_t stream) {
  const float* x = (const float*)d_in[0];
  const float* Wq = (const float*)d_in[1];
  const float* Wkv = (const float*)d_in[2];
  const float* Wproj = (const float*)d_in[3];
  const float* bproj = (const float*)d_in[4];
  float* ws = (float*)d_ws;

  // workspace layout (floats):
  // u[B][H][C]            262144
  // spart[4][B][H][N]     4*1048576
  // p[B][N][H]            1048576
  // l[B][H]               256
  // wpart[B][S][H][C]     S*262144
  // w[B][H][C]            262144
  // cls[B][HD]            16384
  const size_t fixed = 262144ull + 4ull * 1048576ull + 1048576ull + 256ull +
                       262144ull + 16384ull;
  int S = 32;
  if (ws_size < (fixed + 32ull * 262144ull) * 4ull) S = 16;
  if (ws_size < (fixed + 16ull * 262144ull) * 4ull) S = 8;

  float* u = ws;
  float* spart = u + 262144;
  float* p = spart + 4ull * 1048576ull;
  float* l = p + 1048576;
  float* wpart = l + 256;
  float* w = wpart + (size_t)S * 262144ull;
  float* cls = w + 262144;

  kA<<<dim3(B_ * H_), dim3(256), 0, stream>>>(x, Wq, Wkv, u);
  kB<<<dim3(1024), dim3(256), 0, stream>>>(x, u, spart);
  kC<<<dim3(B_ * H_), dim3(256), 0, stream>>>(spart, p, l);
  kD<<<dim3(S, B_), dim3(256), 0, stream>>>(x, p, wpart, N_ / S);
  kR<<<dim3(1024), dim3(256), 0, stream>>>(wpart, l, w, S);
  kE1<<<dim3(64), dim3(256), 0, stream>>>(w, Wkv, cls);
  kE2<<<dim3(64), dim3(256), 0, stream>>>(cls, Wproj, bproj, (float*)d_out);
}

// Round 2
// 514.102 us; speedup vs baseline: 1.4397x; 1.4397x over previous
//
#include <hip/hip_runtime.h>
#include <cstddef>
#include <cstdint>

#define B_ 16
#define N_ 4096
#define C_ 1024
#define H_ 16
#define D_ 64
#define HD_ 1024

// async global->LDS, 16B per lane. g includes the lane offset; LDS dest is
// wave-uniform base + lane*16 (hardware adds it).
__device__ __forceinline__ void stage16(const float* g, float* l, int lane) {
#if __has_builtin(__builtin_amdgcn_global_load_lds)
  __builtin_amdgcn_global_load_lds(
      (const __attribute__((address_space(1))) void*)g,
      (__attribute__((address_space(3))) void*)l, 16, 0, 0);
#else
  *(float4*)(l + lane * 4) = *(const float4*)g;
#endif
}

// ---------------------------------------------------------------------------
// Kernel A (unchanged, correct): per (b,h):
//   q = x[b,0,:] @ Wq_h scaled; u[b,h,c] = sum_d q[d] * Wkv[c, h*64+d]
// ---------------------------------------------------------------------------
__global__ __launch_bounds__(256) void kA(const float* __restrict__ x,
                                          const float* __restrict__ Wq,
                                          const float* __restrict__ Wkv,
                                          float* __restrict__ u) {
  const int b = blockIdx.x >> 4;
  const int h = blockIdx.x & 15;
  __shared__ float xr[C_];
  __shared__ float qp[4][D_];
  __shared__ float qs[D_];
  const float* xb = x + (size_t)b * N_ * C_;  // row n=0
  for (int c = threadIdx.x; c < C_; c += 256) xr[c] = xb[c];
  __syncthreads();
  const int d = threadIdx.x & 63;
  const int part = threadIdx.x >> 6;
  float a = 0.f;
  const float* wq = Wq + h * D_ + d;
  #pragma unroll 4
  for (int c = part * 256; c < part * 256 + 256; ++c)
    a += xr[c] * wq[(size_t)c * HD_];
  qp[part][d] = a;
  __syncthreads();
  if (threadIdx.x < 64) {
    qs[threadIdx.x] = (qp[0][threadIdx.x] + qp[1][threadIdx.x] +
                       qp[2][threadIdx.x] + qp[3][threadIdx.x]) * 0.125f;
  }
  __syncthreads();
  for (int c = threadIdx.x; c < C_; c += 256) {
    const float4* wr = (const float4*)(Wkv + (size_t)c * (2 * HD_) + h * D_);
    float s = 0.f;
    #pragma unroll
    for (int d4 = 0; d4 < 16; ++d4) {
      float4 wv = wr[d4];
      s += wv.x * qs[4 * d4] + wv.y * qs[4 * d4 + 1] +
           wv.z * qs[4 * d4 + 2] + wv.w * qs[4 * d4 + 3];
    }
    u[(size_t)blockIdx.x * C_ + c] = s;
  }
}

// ---------------------------------------------------------------------------
// Fused kernel: single pass over x. Block = (chunk, b), 4 waves.
// Wave w owns heads w*4..w*4+3, full C (lane holds c = q*256 + 4*lane).
// Online softmax per head; acc[h][c] = sum_n exp(s-m) x[n,c].
// x staged to LDS (double-buffered groups of 8 rows) via global_load_lds.
// ---------------------------------------------------------------------------
__global__ __launch_bounds__(256, 2) void kF(const float* __restrict__ x,
                                             const float* __restrict__ u,
                                             float* __restrict__ wpart,
                                             float* __restrict__ mbuf,
                                             float* __restrict__ lbuf,
                                             int G) {
  const int b = blockIdx.y;
  const int chunk = blockIdx.x;
  const int CH = gridDim.x;
  const int tid = threadIdx.x;
  const int w = tid >> 6;
  const int lane = tid & 63;
  __shared__ float xs[2][8][C_];  // 64 KB

  // u fragments for this wave's 4 heads
  float4 uf[4][4];
  const float* ub = u + (size_t)(b * H_ + w * 4) * C_;
  #pragma unroll
  for (int hh = 0; hh < 4; ++hh)
    #pragma unroll
    for (int q = 0; q < 4; ++q)
      uf[hh][q] = *(const float4*)(ub + (size_t)hh * C_ + q * 256 + lane * 4);

  float4 acc[4][4];
  #pragma unroll
  for (int hh = 0; hh < 4; ++hh)
    #pragma unroll
    for (int q = 0; q < 4; ++q) acc[hh][q] = make_float4(0.f, 0.f, 0.f, 0.f);
  float m[4] = {-1e30f, -1e30f, -1e30f, -1e30f};
  float l[4] = {0.f, 0.f, 0.f, 0.f};

  const float* xb = x + ((size_t)b * N_ + (size_t)chunk * G * 8) * C_;

  // preload group 0
  #pragma unroll
  for (int r = 0; r < 8; ++r)
    stage16(xb + (size_t)r * C_ + w * 256 + lane * 4, &xs[0][r][w * 256], lane);

  for (int g = 0; g < G; ++g) {
    __syncthreads();  // loads for group g complete; buf (g+1)&1 free
    if (g + 1 < G) {
      const float* xg = xb + (size_t)(g + 1) * 8 * C_;
      const int nb = (g + 1) & 1;
      #pragma unroll
      for (int r = 0; r < 8; ++r)
        stage16(xg + (size_t)r * C_ + w * 256 + lane * 4, &xs[nb][r][w * 256],
                lane);
    }
    const int buf = g & 1;
    #pragma unroll
    for (int r = 0; r < 8; ++r) {
      float4 xq[4];
      #pragma unroll
      for (int q = 0; q < 4; ++q)
        xq[q] = *(const float4*)&xs[buf][r][q * 256 + lane * 4];
      float ph[4];
      #pragma unroll
      for (int hh = 0; hh < 4; ++hh) {
        float a = 0.f;
        #pragma unroll
        for (int q = 0; q < 4; ++q)
          a += xq[q].x * uf[hh][q].x + xq[q].y * uf[hh][q].y +
               xq[q].z * uf[hh][q].z + xq[q].w * uf[hh][q].w;
        ph[hh] = a;
      }
      // butterfly: every lane ends with the full dot for each head
      #pragma unroll
      for (int mask = 1; mask < 64; mask <<= 1) {
        #pragma unroll
        for (int hh = 0; hh < 4; ++hh) ph[hh] += __shfl_xor(ph[hh], mask);
      }
      float mn[4];
      #pragma unroll
      for (int hh = 0; hh < 4; ++hh) mn[hh] = fmaxf(m[hh], ph[hh]);
      // wave-uniform branch (all lanes hold identical m/ph)
      if (mn[0] > m[0] || mn[1] > m[1] || mn[2] > m[2] || mn[3] > m[3]) {
        #pragma unroll
        for (int hh = 0; hh < 4; ++hh) {
          const float alpha = __expf(m[hh] - mn[hh]);
          l[hh] *= alpha;
          #pragma unroll
          for (int q = 0; q < 4; ++q) {
            acc[hh][q].x *= alpha; acc[hh][q].y *= alpha;
            acc[hh][q].z *= alpha; acc[hh][q].w *= alpha;
          }
          m[hh] = mn[hh];
        }
      }
      #pragma unroll
      for (int hh = 0; hh < 4; ++hh) {
        const float p = __expf(ph[hh] - m[hh]);
        l[hh] += p;
        #pragma unroll
        for (int q = 0; q < 4; ++q) {
          acc[hh][q].x += p * xq[q].x; acc[hh][q].y += p * xq[q].y;
          acc[hh][q].z += p * xq[q].z; acc[hh][q].w += p * xq[q].w;
        }
      }
    }
  }

  float* wp = wpart + ((size_t)(b * CH + chunk) * H_ + w * 4) * C_;
  #pragma unroll
  for (int hh = 0; hh < 4; ++hh)
    #pragma unroll
    for (int q = 0; q < 4; ++q)
      *(float4*)(wp + (size_t)hh * C_ + q * 256 + lane * 4) = acc[hh][q];
  if (lane == 0) {
    #pragma unroll
    for (int hh = 0; hh < 4; ++hh) {
      mbuf[(b * CH + chunk) * H_ + w * 4 + hh] = m[hh];
      lbuf[(b * CH + chunk) * H_ + w * 4 + hh] = l[hh];
    }
  }
}

// ---------------------------------------------------------------------------
// Merge partials: w[b,h,c] = sum_s exp(m_s-M) acc_s[c] / (sum_s exp(m_s-M) l_s)
// grid = 256 blocks (b,h), 256 threads (thread owns 4 c)
// ---------------------------------------------------------------------------
__global__ __launch_bounds__(256) void kM(const float* __restrict__ wpart,
                                          const float* __restrict__ mbuf,
                                          const float* __restrict__ lbuf,
                                          float* __restrict__ w, int CH) {
  const int b = blockIdx.x >> 4;
  const int h = blockIdx.x & 15;
  const int t = threadIdx.x;
  __shared__ float alph[64];
  __shared__ float Linv;
  if (t < 64) {
    float mv = (t < CH) ? mbuf[(b * CH + t) * H_ + h] : -1e30f;
    float M = mv;
    #pragma unroll
    for (int mask = 1; mask < 64; mask <<= 1)
      M = fmaxf(M, __shfl_xor(M, mask));
    const float lv = (t < CH) ? lbuf[(b * CH + t) * H_ + h] : 0.f;
    const float a = __expf(mv - M);
    alph[t] = a;
    float L = a * lv;
    #pragma unroll
    for (int mask = 1; mask < 64; mask <<= 1) L += __shfl_xor(L, mask);
    if (t == 0) Linv = 1.f / L;
  }
  __syncthreads();
  float4 sum = make_float4(0.f, 0.f, 0.f, 0.f);
  for (int s = 0; s < CH; ++s) {
    const float a = alph[s];
    const float4 v =
        *(const float4*)(wpart + ((size_t)(b * CH + s) * H_ + h) * C_ + t * 4);
    sum.x += a * v.x; sum.y += a * v.y; sum.z += a * v.z; sum.w += a * v.w;
  }
  const float li = Linv;
  float4 o = make_float4(sum.x * li, sum.y * li, sum.z * li, sum.w * li);
  *(float4*)(w + (size_t)(b * H_ + h) * C_ + t * 4) = o;
}

// ---------------------------------------------------------------------------
// E1: cls[b,hd] = w[b,h,:] . Wkv[:, 1024+hd]  (h = hd>>6)
// grid 256 = (b, head-group); 4-way c-split + LDS combine
// ---------------------------------------------------------------------------
__global__ __launch_bounds__(256) void kE1(const float* __restrict__ w,
                                           const float* __restrict__ Wkv,
                                           float* __restrict__ cls) {
  const int b = blockIdx.x >> 4;
  const int g = blockIdx.x & 15;  // head index
  const int t = threadIdx.x;
  const int j = t & 63;
  const int part = t >> 6;
  const float* wr = w + (size_t)(b * H_ + g) * C_ + part * 256;
  const float* wv = Wkv + 1024 + g * 64 + j;
  float acc = 0.f;
  #pragma unroll 8
  for (int c = 0; c < 256; ++c)
    acc += wr[c] * wv[(size_t)(part * 256 + c) * 2048];
  __shared__ float red[256];
  red[t] = acc;
  __syncthreads();
  if (t < 64) {
    const float s = red[t] + red[t + 64] + red[t + 128] + red[t + 192];
    cls[(size_t)b * HD_ + g * 64 + t] = s;
  }
}

// ---------------------------------------------------------------------------
// E2: out[b,j] = bproj[j] + cls[b,:] . Wproj[:,j]
// grid 256 = (b, j-group); 4-way i-split + LDS combine
// ---------------------------------------------------------------------------
__global__ __launch_bounds__(256) void kE2(const float* __restrict__ cls,
                                           const float* __restrict__ Wproj,
                                           const float* __restrict__ bproj,
                                           float* __restrict__ out) {
  const int b = blockIdx.x >> 4;
  const int g = blockIdx.x & 15;
  const int t = threadIdx.x;
  const int j = g * 64 + (t & 63);
  const int part = t >> 6;
  const float* cb = cls + (size_t)b * HD_ + part * 256;
  float acc = 0.f;
  #pragma unroll 8
  for (int i = 0; i < 256; ++i)
    acc += cb[i] * Wproj[(size_t)(part * 256 + i) * C_ + j];
  __shared__ float red[256];
  red[t] = acc;
  __syncthreads();
  if (t < 64) {
    const float s =
        red[t] + red[t + 64] + red[t + 128] + red[t + 192] + bproj[g * 64 + t];
    out[(size_t)b * C_ + g * 64 + t] = s;
  }
}

extern "C" void kernel_launch(void* const* d_in, const int* in_sizes, int n_in,
                              void* d_out, int out_size, void* d_ws,
                              size_t ws_size, hipStream_t stream) {
  const float* x = (const float*)d_in[0];
  const float* Wq = (const float*)d_in[1];
  const float* Wkv = (const float*)d_in[2];
  const float* Wproj = (const float*)d_in[3];
  const float* bproj = (const float*)d_in[4];
  float* ws = (float*)d_ws;

  // pick CH (chunks per batch) to fit workspace:
  // floats = u(262144) + wpart(CH*262144) + mbuf/lbuf(2*CH*256)
  //          + w(262144) + cls(16384)
  int CH = 64;
  for (;;) {
    size_t fl = 262144ull + (size_t)CH * 262144ull + 2ull * CH * 256ull +
                262144ull + 16384ull;
    if (fl * 4ull <= ws_size || CH == 8) break;
    CH >>= 1;
  }
  const int G = N_ / (CH * 8);  // 8-row groups per block

  float* u = ws;
  float* wpart = u + 262144;
  float* mbuf = wpart + (size_t)CH * 262144ull;
  float* lbuf = mbuf + (size_t)CH * 256ull;
  float* w = lbuf + (size_t)CH * 256ull;
  float* cls = w + 262144;

  kA<<<dim3(B_ * H_), dim3(256), 0, stream>>>(x, Wq, Wkv, u);
  kF<<<dim3(CH, B_), dim3(256), 0, stream>>>(x, u, wpart, mbuf, lbuf, G);
  kM<<<dim3(256), dim3(256), 0, stream>>>(wpart, mbuf, lbuf, w, CH);
  kE1<<<dim3(256), dim3(256), 0, stream>>>(w, Wkv, cls);
  kE2<<<dim3(256), dim3(256), 0, stream>>>(cls, Wproj, bproj, (float*)d_out);
}